// Round 1
// 678.205 us; speedup vs baseline: 1.0090x; 1.0090x over previous
//
#include <hip/hip_runtime.h>
#include <stdint.h>
#include <math.h>

// ===========================================================================
// MeshLoss: bit-exact JAX threefry sampling + two-way chamfer.
// Round-6: 4-way interleaved threefry in cat_kernel (ILP fix).
//   Theory: VALUBusy~96% is gfx94x-formula-inflated 2x; VGPR=16 shows the
//   loop was register-starved into a serial dependence chain. 4 independent
//   71-op threefry chains per trip + launch_bounds(256,4) + compile-time
//   quarter stride (FC padded to 576-face chunks, pad r=+inf never wins).
// Score: argmax(g + logA) == argmin via fma(-log2(bits), r, 32r), packed
// with 14-bit face index, uint atomicMin.
// ===========================================================================

#define NB 4       // batches
#define NV 6890    // vertices per mesh
#define NF 13776   // faces per mesh
#define NS 4096    // samples per mesh (P_SAMPLE)
#define NCH 24     // j-chunks
#define NFP 13824  // padded faces per mesh (24 * 576)
#define CHLP 576   // padded chunk length
#define QL 144     // quarter stride (576/4), compile-time for ds offsets
#define IDXMASK 0x3FFFu

struct Keys {
  uint32_t k1[2 * NB];
  uint32_t k2[2 * NB];
  uint32_t k3[2 * NB];
};

__host__ __device__ __forceinline__ uint32_t rotl32(uint32_t x, uint32_t n) {
#ifdef __HIP_DEVICE_COMPILE__
  return __builtin_amdgcn_alignbit(x, x, 32u - n);   // single v_alignbit_b32
#else
  return (x << n) | (x >> (32u - n));
#endif
}

// Threefry-2x32, 20 rounds, exactly JAX's schedule (scalar form: host + pts).
__host__ __device__ __forceinline__ void tf2x32(uint32_t k0, uint32_t k1,
                                                uint32_t c0, uint32_t c1,
                                                uint32_t& o0, uint32_t& o1) {
  uint32_t ks2 = k0 ^ k1 ^ 0x1BD11BDAu;
  uint32_t x0 = c0 + k0, x1 = c1 + k1;
#define R4(a, b, c, d)                                   \
  { x0 += x1; x1 = rotl32(x1, a); x1 ^= x0;              \
    x0 += x1; x1 = rotl32(x1, b); x1 ^= x0;              \
    x0 += x1; x1 = rotl32(x1, c); x1 ^= x0;              \
    x0 += x1; x1 = rotl32(x1, d); x1 ^= x0; }
  R4(13, 15, 26, 6)  x0 += k1;  x1 += ks2 + 1u;
  R4(17, 29, 16, 24) x0 += ks2; x1 += k0 + 2u;
  R4(13, 15, 26, 6)  x0 += k0;  x1 += k1 + 3u;
  R4(17, 29, 16, 24) x0 += k1;  x1 += ks2 + 4u;
  R4(13, 15, 26, 6)  x0 += ks2; x1 += k0 + 5u;
#undef R4
  o0 = x0; o1 = x1;
}

// 4-wide interleaved threefry: 4 independent chains, rounds interleaved so
// dependent ops are >=4 instructions apart. Returns o = x0^x1 per chain.
__device__ __forceinline__ void tf2x32_x4(uint32_t k0, uint32_t k1,
                                          uint32_t c1a, uint32_t c1b,
                                          uint32_t c1c, uint32_t c1d,
                                          uint32_t o[4]) {
  uint32_t ks2 = k0 ^ k1 ^ 0x1BD11BDAu;
  uint32_t x0[4], x1[4];
  uint32_t c1[4] = {c1a, c1b, c1c, c1d};
#pragma unroll
  for (int m = 0; m < 4; ++m) { x0[m] = k0; x1[m] = c1[m] + k1; }
#define RR(n)                                                     \
  _Pragma("unroll")                                               \
  for (int m = 0; m < 4; ++m) {                                   \
    x0[m] += x1[m]; x1[m] = rotl32(x1[m], n); x1[m] ^= x0[m];     \
  }
#define INJ(a, b)                                                 \
  _Pragma("unroll")                                               \
  for (int m = 0; m < 4; ++m) { x0[m] += (a); x1[m] += (b); }
  RR(13) RR(15) RR(26) RR(6)  INJ(k1, ks2 + 1u)
  RR(17) RR(29) RR(16) RR(24) INJ(ks2, k0 + 2u)
  RR(13) RR(15) RR(26) RR(6)  INJ(k0, k1 + 3u)
  RR(17) RR(29) RR(16) RR(24) INJ(k1, ks2 + 4u)
  RR(13) RR(15) RR(26) RR(6)  INJ(ks2, k0 + 5u)
#undef RR
#undef INJ
#pragma unroll
  for (int m = 0; m < 4; ++m) o[m] = x0[m] ^ x1[m];
}

__device__ __forceinline__ float unit_from_bits(uint32_t bits) {
  return __uint_as_float((bits >> 9) | 0x3f800000u) - 1.0f;
}

__device__ __forceinline__ float raw_log2(float x) {
  float r;
  asm("v_log_f32 %0, %1" : "=v"(r) : "v"(x));
  return r;
}

__device__ __forceinline__ uint32_t min3_u32(uint32_t a, uint32_t b, uint32_t c) {
  uint32_t r;
  asm("v_min3_u32 %0, %1, %2, %3" : "=v"(r) : "v"(a), "v"(b), "v"(c));
  return r;
}

// ---------------------------------------------------------------------------
// Kernel A: per-face float4 (rP, 32*rP, rG, 32*rG), r = 1/(area+1e-12).
// Padded layout: NFP entries/batch; pad entries get +inf (packed key then
// lands >= 0x7F800000 and always loses the uint argmin; ties break to
// smaller j = real faces).
// ---------------------------------------------------------------------------
__global__ __launch_bounds__(256) void area_kernel(
    const float* __restrict__ pv, const int* __restrict__ pf,
    const float* __restrict__ gv, const int* __restrict__ gf,
    float4* __restrict__ FC) {
  int idx = blockIdx.x * 256 + threadIdx.x;
  if (idx >= NB * NFP) return;
  int b = idx / NFP;
  int f = idx - b * NFP;
  if (f >= NF) {
    float inf = __uint_as_float(0x7F800000u);
    FC[idx] = make_float4(inf, inf, inf, inf);
    return;
  }
  float r2[2];
#pragma unroll
  for (int half = 0; half < 2; ++half) {
    const float* verts = half == 0 ? pv + (size_t)b * NV * 3 : gv + (size_t)b * NV * 3;
    const int* faces   = half == 0 ? pf + (size_t)b * NF * 3 : gf + (size_t)b * NF * 3;
    int i0 = faces[3 * f + 0], i1 = faces[3 * f + 1], i2 = faces[3 * f + 2];
    float ax = verts[3 * i0], ay = verts[3 * i0 + 1], az = verts[3 * i0 + 2];
    float bx = verts[3 * i1], by = verts[3 * i1 + 1], bz = verts[3 * i1 + 2];
    float cx = verts[3 * i2], cy = verts[3 * i2 + 1], cz = verts[3 * i2 + 2];
    float e1x = bx - ax, e1y = by - ay, e1z = bz - az;
    float e2x = cx - ax, e2y = cy - ay, e2z = cz - az;
    float nx = e1y * e2z - e1z * e2y;
    float ny = e1z * e2x - e1x * e2z;
    float nz = e1x * e2y - e1y * e2x;
    float area = 0.5f * sqrtf(nx * nx + ny * ny + nz * nz);
    r2[half] = 1.0f / (area + 1e-12f);
  }
  FC[idx] = make_float4(r2[0], 32.0f * r2[0], r2[1], 32.0f * r2[1]);
}

// ---------------------------------------------------------------------------
// Kernel B: categorical sampling.  grid = rowgrp(64) x chunk(24).
// Block: 256 threads = 256 rows (one batch), one padded j-chunk of 576.
// 4-way interleaved threefry per trip; QL=144 compile-time quarter stride.
// ---------------------------------------------------------------------------
__global__ __launch_bounds__(256, 4) void cat_kernel(
    const float4* __restrict__ FC, unsigned int* __restrict__ mb, Keys K) {
  __shared__ float4 sFC[CHLP];
  int chunk = blockIdx.x % NCH;
  int rowgrp = blockIdx.x / NCH;        // [0, 64)
  int row = rowgrp * 256 + threadIdx.x; // [0, 16384)
  int b = rowgrp >> 4;                  // uniform per block
  int i = row & (NS - 1);
  int jstart = chunk * CHLP;
  uint32_t k0 = K.k1[2 * b], k1 = K.k1[2 * b + 1];

  const float4* __restrict__ fcg = FC + (size_t)b * NFP + jstart;
  for (int t = threadIdx.x; t < CHLP; t += 256) sFC[t] = fcg[t];
  __syncthreads();

  uint32_t cbase = (uint32_t)i * (uint32_t)NF + (uint32_t)jstart;
  uint32_t bestP = 0xFFFFFFFFu, bestG = 0xFFFFFFFFu;

  for (int k = 0; k < QL; ++k) {
    uint32_t o[4];
    // face j = jstart + k + m*QL; counter = i*NF + j (identical bits to ref)
    tf2x32_x4(k0, k1,
              cbase + (uint32_t)k,
              cbase + (uint32_t)(k + QL),
              cbase + (uint32_t)(k + 2 * QL),
              cbase + (uint32_t)(k + 3 * QL), o);
    uint32_t kp[4], kg[4];
#pragma unroll
    for (int m = 0; m < 4; ++m) {
      float f1 = (float)o[m];              // v_cvt_f32_u32
      float l1 = raw_log2(f1);             // bits=0 -> -inf -> +inf key, loses
      float4 r1 = sFC[k + m * QL];         // lane-uniform ds_read_b128, imm offs
      uint32_t jj = (uint32_t)(jstart + k + m * QL);
      // score = 32*r - log2(bits)*r  (>= 0), single v_fma with -src modifier
      kp[m] = (__float_as_uint(fmaf(-l1, r1.x, r1.y)) & ~IDXMASK) | jj;
      kg[m] = (__float_as_uint(fmaf(-l1, r1.z, r1.w)) & ~IDXMASK) | jj;
    }
    bestP = min3_u32(min3_u32(bestP, kp[0], kp[1]), kp[2], kp[3]);
    bestG = min3_u32(min3_u32(bestG, kg[0], kg[1]), kg[2], kg[3]);
  }
  atomicMin(&mb[row], bestP);
  atomicMin(&mb[NB * NS + row], bestG);
}

// ---------------------------------------------------------------------------
// Kernel C: build sampled points for all 8 meshes. u,w shared pred/gt.
// ---------------------------------------------------------------------------
__global__ __launch_bounds__(256) void pts_kernel(
    const float* __restrict__ pv, const int* __restrict__ pf,
    const float* __restrict__ gv, const int* __restrict__ gf,
    const unsigned int* __restrict__ mb, float* __restrict__ pts, Keys K) {
  int idx = blockIdx.x * 256 + threadIdx.x;
  if (idx >= NB * NS) return;
  int b = idx >> 12;
  int i = idx & (NS - 1);

  uint32_t a0, a1, ub, wb;
  tf2x32(K.k2[2 * b], K.k2[2 * b + 1], 0u, (uint32_t)i, a0, a1); ub = a0 ^ a1;
  tf2x32(K.k3[2 * b], K.k3[2 * b + 1], 0u, (uint32_t)i, a0, a1); wb = a0 ^ a1;

  float u = unit_from_bits(ub);
  float w = unit_from_bits(wb);
  float r = sqrtf(u);
  float c0 = 1.0f - r;
  float c1 = r * (1.0f - w);
  float c2 = r * w;

#pragma unroll
  for (int half = 0; half < 2; ++half) {
    const float* verts = half == 0 ? pv + (size_t)b * NV * 3 : gv + (size_t)b * NV * 3;
    const int* faces   = half == 0 ? pf + (size_t)b * NF * 3 : gf + (size_t)b * NF * 3;
    int mesh = half == 0 ? b : NB + b;
    int f = (int)(mb[(size_t)mesh * NS + i] & IDXMASK);
    int i0 = faces[3 * f + 0], i1 = faces[3 * f + 1], i2 = faces[3 * f + 2];
    float* dst = pts + ((size_t)mesh * NS + i) * 3;
#pragma unroll
    for (int c = 0; c < 3; ++c) {
      float v0 = verts[3 * i0 + c];
      float v1 = verts[3 * i1 + c];
      float v2 = verts[3 * i2 + c];
      dst[c] = c0 * v0 + c1 * v1 + c2 * v2;
    }
  }
}

// ---------------------------------------------------------------------------
// Kernel D: two-way chamfer partial-min. 1024 blocks; 512-pt LDS DB tile.
// ---------------------------------------------------------------------------
#define DBC 8
#define DBL (NS / DBC)   // 512
__global__ __launch_bounds__(256) void chamfer_min_kernel(
    const float* __restrict__ pts, unsigned int* __restrict__ cmin) {
  int blk = blockIdx.x;
  int dchunk = blk & (DBC - 1);
  int rest = blk >> 3;
  int chunk = rest & 15;
  int mb_ = rest >> 4;
  int dir = mb_ >> 2, b = mb_ & 3;
  int qm = (dir == 0) ? b : NB + b;
  int dm = (dir == 0) ? NB + b : b;

  __shared__ float4 db[DBL];
  const float* dbp = pts + ((size_t)dm * NS + dchunk * DBL) * 3;
  for (int j = threadIdx.x; j < DBL; j += 256) {
    float x = dbp[3 * j], y = dbp[3 * j + 1], z = dbp[3 * j + 2];
    db[j] = make_float4(x, y, z, x * x + y * y + z * z);
  }
  __syncthreads();

  int q = chunk * 256 + threadIdx.x;
  const float* qp = pts + ((size_t)qm * NS + q) * 3;
  float px = qp[0], py = qp[1], pz = qp[2];
  float pp = px * px + py * py + pz * pz;
  float m = INFINITY;
  for (int j = 0; j < DBL; ++j) {
    float4 t = db[j];
    float d = (pp + t.w) - 2.0f * (px * t.x + py * t.y + pz * t.z);
    m = fminf(m, d);
  }
  m = fmaxf(m, 0.0f);
  atomicMin(&cmin[(size_t)(dir * NB + b) * NS + q], __float_as_uint(m));
}

// ---------------------------------------------------------------------------
// Kernel E: sum 2*NB*NS mins -> loss.  64 blocks, wave-reduce + atomicAdd.
// ---------------------------------------------------------------------------
__global__ __launch_bounds__(256) void chamfer_sum_kernel(
    const unsigned int* __restrict__ cmin, float* __restrict__ out) {
  int idx = blockIdx.x * 256 + threadIdx.x;
  float s = __uint_as_float(cmin[idx]) + __uint_as_float(cmin[idx + 16384]);
  for (int off = 32; off > 0; off >>= 1) s += __shfl_down(s, off);
  if ((threadIdx.x & 63) == 0) atomicAdd(out, s * (1.0f / 16384.0f));
}

// ---------------------------------------------------------------------------
extern "C" void kernel_launch(void* const* d_in, const int* in_sizes, int n_in,
                              void* d_out, int out_size, void* d_ws, size_t ws_size,
                              hipStream_t stream) {
  const float* pv = (const float*)d_in[0];
  const int* pf = (const int*)d_in[1];
  const float* gv = (const float*)d_in[2];
  const int* gf = (const int*)d_in[3];
  float* out = (float*)d_out;

  float4* FC = (float4*)d_ws;                                      // 884,736 B
  unsigned int* mb = (unsigned int*)((char*)d_ws + 896 * 1024);    // 131,072 B
  unsigned int* cmin = (unsigned int*)((char*)d_ws + 1024 * 1024); // 131,072 B
  float* pts = (float*)((char*)d_ws + 1152 * 1024);                // 393,216 B

  Keys K;
  for (int b = 0; b < NB; ++b) {
    uint32_t kb0, kb1;
    tf2x32(0u, 42u, 0u, (uint32_t)b, kb0, kb1);
    tf2x32(kb0, kb1, 0u, 0u, K.k1[2 * b], K.k1[2 * b + 1]);
    tf2x32(kb0, kb1, 0u, 1u, K.k2[2 * b], K.k2[2 * b + 1]);
    tf2x32(kb0, kb1, 0u, 2u, K.k3[2 * b], K.k3[2 * b + 1]);
  }

  hipMemsetAsync(mb, 0xFF, 256 * 1024, stream);   // both min buffers
  hipMemsetAsync(out, 0, sizeof(float), stream);

  area_kernel<<<(NB * NFP) / 256, 256, 0, stream>>>(pv, pf, gv, gf, FC);
  cat_kernel<<<64 * NCH, 256, 0, stream>>>(FC, mb, K);   // 1536 blocks
  pts_kernel<<<(NB * NS + 255) / 256, 256, 0, stream>>>(pv, pf, gv, gf, mb, pts, K);
  chamfer_min_kernel<<<2 * NB * 16 * DBC, 256, 0, stream>>>(pts, cmin);
  chamfer_sum_kernel<<<64, 256, 0, stream>>>(cmin, out);
}

// Round 2
// 670.087 us; speedup vs baseline: 1.0212x; 1.0121x over previous
//
#include <hip/hip_runtime.h>
#include <stdint.h>
#include <math.h>

// ===========================================================================
// MeshLoss: bit-exact JAX threefry sampling + two-way chamfer.
// Round-7: occupancy fix. R6 post-mortem: 4-way ILP changed nothing ->
// not intra-wave-latency-bound at current residency. True VALU issue ~48%
// (VALUBusy=96% is gfx94x 4cy-formula, gfx950 is 2cy). Occupancy 42% =
// ~3.4 waves/SIMD (grid was only 6 blocks/CU). Fix: split j-chunks 24->48
// (3072 blocks, 12/CU, residency caps at 8 blocks = 32 waves/CU).
// Score: argmax(g + logA) == argmin via fma(-log2(bits), r, 32r), packed
// with 14-bit face index, uint atomicMin.
// ===========================================================================

#define NB 4       // batches
#define NV 6890    // vertices per mesh
#define NF 13776   // faces per mesh
#define NS 4096    // samples per mesh (P_SAMPLE)
#define NCH 48     // j-chunks
#define NFP 13824  // padded faces per mesh (48 * 288)
#define CHLP 288   // padded chunk length
#define QL 72      // quarter stride (288/4), compile-time for ds offsets
#define IDXMASK 0x3FFFu

struct Keys {
  uint32_t k1[2 * NB];
  uint32_t k2[2 * NB];
  uint32_t k3[2 * NB];
};

__host__ __device__ __forceinline__ uint32_t rotl32(uint32_t x, uint32_t n) {
#ifdef __HIP_DEVICE_COMPILE__
  return __builtin_amdgcn_alignbit(x, x, 32u - n);   // single v_alignbit_b32
#else
  return (x << n) | (x >> (32u - n));
#endif
}

// Threefry-2x32, 20 rounds, exactly JAX's schedule (scalar form: host + pts).
__host__ __device__ __forceinline__ void tf2x32(uint32_t k0, uint32_t k1,
                                                uint32_t c0, uint32_t c1,
                                                uint32_t& o0, uint32_t& o1) {
  uint32_t ks2 = k0 ^ k1 ^ 0x1BD11BDAu;
  uint32_t x0 = c0 + k0, x1 = c1 + k1;
#define R4(a, b, c, d)                                   \
  { x0 += x1; x1 = rotl32(x1, a); x1 ^= x0;              \
    x0 += x1; x1 = rotl32(x1, b); x1 ^= x0;              \
    x0 += x1; x1 = rotl32(x1, c); x1 ^= x0;              \
    x0 += x1; x1 = rotl32(x1, d); x1 ^= x0; }
  R4(13, 15, 26, 6)  x0 += k1;  x1 += ks2 + 1u;
  R4(17, 29, 16, 24) x0 += ks2; x1 += k0 + 2u;
  R4(13, 15, 26, 6)  x0 += k0;  x1 += k1 + 3u;
  R4(17, 29, 16, 24) x0 += k1;  x1 += ks2 + 4u;
  R4(13, 15, 26, 6)  x0 += ks2; x1 += k0 + 5u;
#undef R4
  o0 = x0; o1 = x1;
}

// 4-wide interleaved threefry: 4 independent chains, rounds interleaved.
// Returns o = x0^x1 per chain (JAX partitionable-threefry output).
__device__ __forceinline__ void tf2x32_x4(uint32_t k0, uint32_t k1,
                                          uint32_t c1a, uint32_t c1b,
                                          uint32_t c1c, uint32_t c1d,
                                          uint32_t o[4]) {
  uint32_t ks2 = k0 ^ k1 ^ 0x1BD11BDAu;
  uint32_t x0[4], x1[4];
  uint32_t c1[4] = {c1a, c1b, c1c, c1d};
#pragma unroll
  for (int m = 0; m < 4; ++m) { x0[m] = k0; x1[m] = c1[m] + k1; }
#define RR(n)                                                     \
  _Pragma("unroll")                                               \
  for (int m = 0; m < 4; ++m) {                                   \
    x0[m] += x1[m]; x1[m] = rotl32(x1[m], n); x1[m] ^= x0[m];     \
  }
#define INJ(a, b)                                                 \
  _Pragma("unroll")                                               \
  for (int m = 0; m < 4; ++m) { x0[m] += (a); x1[m] += (b); }
  RR(13) RR(15) RR(26) RR(6)  INJ(k1, ks2 + 1u)
  RR(17) RR(29) RR(16) RR(24) INJ(ks2, k0 + 2u)
  RR(13) RR(15) RR(26) RR(6)  INJ(k0, k1 + 3u)
  RR(17) RR(29) RR(16) RR(24) INJ(k1, ks2 + 4u)
  RR(13) RR(15) RR(26) RR(6)  INJ(ks2, k0 + 5u)
#undef RR
#undef INJ
#pragma unroll
  for (int m = 0; m < 4; ++m) o[m] = x0[m] ^ x1[m];
}

__device__ __forceinline__ float unit_from_bits(uint32_t bits) {
  return __uint_as_float((bits >> 9) | 0x3f800000u) - 1.0f;
}

__device__ __forceinline__ float raw_log2(float x) {
  float r;
  asm("v_log_f32 %0, %1" : "=v"(r) : "v"(x));
  return r;
}

__device__ __forceinline__ uint32_t min3_u32(uint32_t a, uint32_t b, uint32_t c) {
  uint32_t r;
  asm("v_min3_u32 %0, %1, %2, %3" : "=v"(r) : "v"(a), "v"(b), "v"(c));
  return r;
}

// ---------------------------------------------------------------------------
// Kernel A: per-face float4 (rP, 32*rP, rG, 32*rG), r = 1/(area+1e-12).
// Padded layout: NFP entries/batch; pad entries get +inf (packed key then
// lands >= 0x7F800000 and always loses the uint argmin; ties break to
// smaller j = real faces).
// ---------------------------------------------------------------------------
__global__ __launch_bounds__(256) void area_kernel(
    const float* __restrict__ pv, const int* __restrict__ pf,
    const float* __restrict__ gv, const int* __restrict__ gf,
    float4* __restrict__ FC) {
  int idx = blockIdx.x * 256 + threadIdx.x;
  if (idx >= NB * NFP) return;
  int b = idx / NFP;
  int f = idx - b * NFP;
  if (f >= NF) {
    float inf = __uint_as_float(0x7F800000u);
    FC[idx] = make_float4(inf, inf, inf, inf);
    return;
  }
  float r2[2];
#pragma unroll
  for (int half = 0; half < 2; ++half) {
    const float* verts = half == 0 ? pv + (size_t)b * NV * 3 : gv + (size_t)b * NV * 3;
    const int* faces   = half == 0 ? pf + (size_t)b * NF * 3 : gf + (size_t)b * NF * 3;
    int i0 = faces[3 * f + 0], i1 = faces[3 * f + 1], i2 = faces[3 * f + 2];
    float ax = verts[3 * i0], ay = verts[3 * i0 + 1], az = verts[3 * i0 + 2];
    float bx = verts[3 * i1], by = verts[3 * i1 + 1], bz = verts[3 * i1 + 2];
    float cx = verts[3 * i2], cy = verts[3 * i2 + 1], cz = verts[3 * i2 + 2];
    float e1x = bx - ax, e1y = by - ay, e1z = bz - az;
    float e2x = cx - ax, e2y = cy - ay, e2z = cz - az;
    float nx = e1y * e2z - e1z * e2y;
    float ny = e1z * e2x - e1x * e2z;
    float nz = e1x * e2y - e1y * e2x;
    float area = 0.5f * sqrtf(nx * nx + ny * ny + nz * nz);
    r2[half] = 1.0f / (area + 1e-12f);
  }
  FC[idx] = make_float4(r2[0], 32.0f * r2[0], r2[1], 32.0f * r2[1]);
}

// ---------------------------------------------------------------------------
// Kernel B: categorical sampling.  grid = rowgrp(64) x chunk(48).
// Block: 256 threads = 256 rows (one batch), one padded j-chunk of 288.
// 4-way interleaved threefry per trip; QL=72 compile-time quarter stride.
// ---------------------------------------------------------------------------
__global__ __launch_bounds__(256, 4) void cat_kernel(
    const float4* __restrict__ FC, unsigned int* __restrict__ mb, Keys K) {
  __shared__ float4 sFC[CHLP];
  int chunk = blockIdx.x % NCH;
  int rowgrp = blockIdx.x / NCH;        // [0, 64)
  int row = rowgrp * 256 + threadIdx.x; // [0, 16384)
  int b = rowgrp >> 4;                  // uniform per block
  int i = row & (NS - 1);
  int jstart = chunk * CHLP;
  uint32_t k0 = K.k1[2 * b], k1 = K.k1[2 * b + 1];

  const float4* __restrict__ fcg = FC + (size_t)b * NFP + jstart;
  for (int t = threadIdx.x; t < CHLP; t += 256) sFC[t] = fcg[t];
  __syncthreads();

  uint32_t cbase = (uint32_t)i * (uint32_t)NF + (uint32_t)jstart;
  uint32_t bestP = 0xFFFFFFFFu, bestG = 0xFFFFFFFFu;

  for (int k = 0; k < QL; ++k) {
    uint32_t o[4];
    // face j = jstart + k + m*QL; counter = i*NF + j (identical bits to ref)
    tf2x32_x4(k0, k1,
              cbase + (uint32_t)k,
              cbase + (uint32_t)(k + QL),
              cbase + (uint32_t)(k + 2 * QL),
              cbase + (uint32_t)(k + 3 * QL), o);
    uint32_t kp[4], kg[4];
#pragma unroll
    for (int m = 0; m < 4; ++m) {
      float f1 = (float)o[m];              // v_cvt_f32_u32
      float l1 = raw_log2(f1);             // bits=0 -> -inf -> +inf key, loses
      float4 r1 = sFC[k + m * QL];         // lane-uniform ds_read_b128, imm offs
      uint32_t jj = (uint32_t)(jstart + k + m * QL);
      // score = 32*r - log2(bits)*r  (>= 0), single v_fma with -src modifier
      kp[m] = (__float_as_uint(fmaf(-l1, r1.x, r1.y)) & ~IDXMASK) | jj;
      kg[m] = (__float_as_uint(fmaf(-l1, r1.z, r1.w)) & ~IDXMASK) | jj;
    }
    bestP = min3_u32(min3_u32(bestP, kp[0], kp[1]), kp[2], kp[3]);
    bestG = min3_u32(min3_u32(bestG, kg[0], kg[1]), kg[2], kg[3]);
  }
  atomicMin(&mb[row], bestP);
  atomicMin(&mb[NB * NS + row], bestG);
}

// ---------------------------------------------------------------------------
// Kernel C: build sampled points for all 8 meshes. u,w shared pred/gt.
// ---------------------------------------------------------------------------
__global__ __launch_bounds__(256) void pts_kernel(
    const float* __restrict__ pv, const int* __restrict__ pf,
    const float* __restrict__ gv, const int* __restrict__ gf,
    const unsigned int* __restrict__ mb, float* __restrict__ pts, Keys K) {
  int idx = blockIdx.x * 256 + threadIdx.x;
  if (idx >= NB * NS) return;
  int b = idx >> 12;
  int i = idx & (NS - 1);

  uint32_t a0, a1, ub, wb;
  tf2x32(K.k2[2 * b], K.k2[2 * b + 1], 0u, (uint32_t)i, a0, a1); ub = a0 ^ a1;
  tf2x32(K.k3[2 * b], K.k3[2 * b + 1], 0u, (uint32_t)i, a0, a1); wb = a0 ^ a1;

  float u = unit_from_bits(ub);
  float w = unit_from_bits(wb);
  float r = sqrtf(u);
  float c0 = 1.0f - r;
  float c1 = r * (1.0f - w);
  float c2 = r * w;

#pragma unroll
  for (int half = 0; half < 2; ++half) {
    const float* verts = half == 0 ? pv + (size_t)b * NV * 3 : gv + (size_t)b * NV * 3;
    const int* faces   = half == 0 ? pf + (size_t)b * NF * 3 : gf + (size_t)b * NF * 3;
    int mesh = half == 0 ? b : NB + b;
    int f = (int)(mb[(size_t)mesh * NS + i] & IDXMASK);
    int i0 = faces[3 * f + 0], i1 = faces[3 * f + 1], i2 = faces[3 * f + 2];
    float* dst = pts + ((size_t)mesh * NS + i) * 3;
#pragma unroll
    for (int c = 0; c < 3; ++c) {
      float v0 = verts[3 * i0 + c];
      float v1 = verts[3 * i1 + c];
      float v2 = verts[3 * i2 + c];
      dst[c] = c0 * v0 + c1 * v1 + c2 * v2;
    }
  }
}

// ---------------------------------------------------------------------------
// Kernel D: two-way chamfer partial-min. 1024 blocks; 512-pt LDS DB tile.
// ---------------------------------------------------------------------------
#define DBC 8
#define DBL (NS / DBC)   // 512
__global__ __launch_bounds__(256) void chamfer_min_kernel(
    const float* __restrict__ pts, unsigned int* __restrict__ cmin) {
  int blk = blockIdx.x;
  int dchunk = blk & (DBC - 1);
  int rest = blk >> 3;
  int chunk = rest & 15;
  int mb_ = rest >> 4;
  int dir = mb_ >> 2, b = mb_ & 3;
  int qm = (dir == 0) ? b : NB + b;
  int dm = (dir == 0) ? NB + b : b;

  __shared__ float4 db[DBL];
  const float* dbp = pts + ((size_t)dm * NS + dchunk * DBL) * 3;
  for (int j = threadIdx.x; j < DBL; j += 256) {
    float x = dbp[3 * j], y = dbp[3 * j + 1], z = dbp[3 * j + 2];
    db[j] = make_float4(x, y, z, x * x + y * y + z * z);
  }
  __syncthreads();

  int q = chunk * 256 + threadIdx.x;
  const float* qp = pts + ((size_t)qm * NS + q) * 3;
  float px = qp[0], py = qp[1], pz = qp[2];
  float pp = px * px + py * py + pz * pz;
  float m = INFINITY;
  for (int j = 0; j < DBL; ++j) {
    float4 t = db[j];
    float d = (pp + t.w) - 2.0f * (px * t.x + py * t.y + pz * t.z);
    m = fminf(m, d);
  }
  m = fmaxf(m, 0.0f);
  atomicMin(&cmin[(size_t)(dir * NB + b) * NS + q], __float_as_uint(m));
}

// ---------------------------------------------------------------------------
// Kernel E: sum 2*NB*NS mins -> loss.  64 blocks, wave-reduce + atomicAdd.
// ---------------------------------------------------------------------------
__global__ __launch_bounds__(256) void chamfer_sum_kernel(
    const unsigned int* __restrict__ cmin, float* __restrict__ out) {
  int idx = blockIdx.x * 256 + threadIdx.x;
  float s = __uint_as_float(cmin[idx]) + __uint_as_float(cmin[idx + 16384]);
  for (int off = 32; off > 0; off >>= 1) s += __shfl_down(s, off);
  if ((threadIdx.x & 63) == 0) atomicAdd(out, s * (1.0f / 16384.0f));
}

// ---------------------------------------------------------------------------
extern "C" void kernel_launch(void* const* d_in, const int* in_sizes, int n_in,
                              void* d_out, int out_size, void* d_ws, size_t ws_size,
                              hipStream_t stream) {
  const float* pv = (const float*)d_in[0];
  const int* pf = (const int*)d_in[1];
  const float* gv = (const float*)d_in[2];
  const int* gf = (const int*)d_in[3];
  float* out = (float*)d_out;

  float4* FC = (float4*)d_ws;                                      // 884,736 B
  unsigned int* mb = (unsigned int*)((char*)d_ws + 896 * 1024);    // 131,072 B
  unsigned int* cmin = (unsigned int*)((char*)d_ws + 1024 * 1024); // 131,072 B
  float* pts = (float*)((char*)d_ws + 1152 * 1024);                // 393,216 B

  Keys K;
  for (int b = 0; b < NB; ++b) {
    uint32_t kb0, kb1;
    tf2x32(0u, 42u, 0u, (uint32_t)b, kb0, kb1);
    tf2x32(kb0, kb1, 0u, 0u, K.k1[2 * b], K.k1[2 * b + 1]);
    tf2x32(kb0, kb1, 0u, 1u, K.k2[2 * b], K.k2[2 * b + 1]);
    tf2x32(kb0, kb1, 0u, 2u, K.k3[2 * b], K.k3[2 * b + 1]);
  }

  hipMemsetAsync(mb, 0xFF, 256 * 1024, stream);   // both min buffers
  hipMemsetAsync(out, 0, sizeof(float), stream);

  area_kernel<<<(NB * NFP) / 256, 256, 0, stream>>>(pv, pf, gv, gf, FC);
  cat_kernel<<<64 * NCH, 256, 0, stream>>>(FC, mb, K);   // 3072 blocks
  pts_kernel<<<(NB * NS + 255) / 256, 256, 0, stream>>>(pv, pf, gv, gf, mb, pts, K);
  chamfer_min_kernel<<<2 * NB * 16 * DBC, 256, 0, stream>>>(pts, cmin);
  chamfer_sum_kernel<<<64, 256, 0, stream>>>(cmin, out);
}

// Round 4
// 526.989 us; speedup vs baseline: 1.2985x; 1.2715x over previous
//
#include <hip/hip_runtime.h>
#include <stdint.h>
#include <math.h>

// ===========================================================================
// MeshLoss: bit-exact JAX threefry sampling + two-way chamfer.
// Round-9: identical to Round-8 (container infra flake, no data returned).
// Instruction diet: R6 (ILP x4) and R7 (occupancy 42->66%) both null =>
// cat_kernel is INTEGER-VALU-pipe-bound (int ALU 4cy/wave64; FP32 got the
// SIMD-32 widening, int didn't). Only lever: fewer instructions/face.
// Fusions: v_add3_u32 for key-injection adds, final injection folded into
// output xor, v_and_or_b32 for score packing, counters kept as
// incrementing registers. ~105 -> ~77 VALU/face.
// Score: argmax(g + logA) == argmin via fma(-log2(bits), r, 32r), packed
// with 14-bit face index, uint atomicMin.
// ===========================================================================

#define NB 4       // batches
#define NV 6890    // vertices per mesh
#define NF 13776   // faces per mesh
#define NS 4096    // samples per mesh (P_SAMPLE)
#define NCH 48     // j-chunks
#define NFP 13824  // padded faces per mesh (48 * 288)
#define CHLP 288   // padded chunk length
#define QL 72      // quarter stride (288/4), compile-time for ds offsets
#define IDXMASK 0x3FFFu

struct Keys {
  uint32_t k1[2 * NB];
  uint32_t k2[2 * NB];
  uint32_t k3[2 * NB];
};

__host__ __device__ __forceinline__ uint32_t rotl32(uint32_t x, uint32_t n) {
#ifdef __HIP_DEVICE_COMPILE__
  return __builtin_amdgcn_alignbit(x, x, 32u - n);   // single v_alignbit_b32
#else
  return (x << n) | (x >> (32u - n));
#endif
}

// Threefry-2x32, 20 rounds, exactly JAX's schedule (scalar form: host + pts).
__host__ __device__ __forceinline__ void tf2x32(uint32_t k0, uint32_t k1,
                                                uint32_t c0, uint32_t c1,
                                                uint32_t& o0, uint32_t& o1) {
  uint32_t ks2 = k0 ^ k1 ^ 0x1BD11BDAu;
  uint32_t x0 = c0 + k0, x1 = c1 + k1;
#define R4(a, b, c, d)                                   \
  { x0 += x1; x1 = rotl32(x1, a); x1 ^= x0;              \
    x0 += x1; x1 = rotl32(x1, b); x1 ^= x0;              \
    x0 += x1; x1 = rotl32(x1, c); x1 ^= x0;              \
    x0 += x1; x1 = rotl32(x1, d); x1 ^= x0; }
  R4(13, 15, 26, 6)  x0 += k1;  x1 += ks2 + 1u;
  R4(17, 29, 16, 24) x0 += ks2; x1 += k0 + 2u;
  R4(13, 15, 26, 6)  x0 += k0;  x1 += k1 + 3u;
  R4(17, 29, 16, 24) x0 += k1;  x1 += ks2 + 4u;
  R4(13, 15, 26, 6)  x0 += ks2; x1 += k0 + 5u;
#undef R4
  o0 = x0; o1 = x1;
}

// v_add3_u32 with wave-uniform middle operand in an SGPR (1 sgpr read: legal)
__device__ __forceinline__ uint32_t add3s(uint32_t a, uint32_t b_sgpr, uint32_t c) {
  uint32_t r;
  asm("v_add3_u32 %0, %1, %2, %3" : "=v"(r) : "v"(a), "s"(b_sgpr), "v"(c));
  return r;
}

// (a & mask) | j in one VOP3; mask is wave-uniform -> SGPR operand
__device__ __forceinline__ uint32_t and_or_s(uint32_t a, uint32_t mask_sgpr, uint32_t j) {
  uint32_t r;
  asm("v_and_or_b32 %0, %1, %2, %3" : "=v"(r) : "v"(a), "s"(mask_sgpr), "v"(j));
  return r;
}

// 4-wide fused threefry: injection adds folded into the next round via
// v_add3_u32; final injection folded into the output xor.
// x1i[m] = c1[m] + k1 (caller-maintained incrementing registers).
// Bn = {ks2+1, k0+2, k1+3, ks2+4, k0+5} (SGPR, precomputed).
__device__ __forceinline__ void tf2x32_x4f(uint32_t k0, uint32_t k1, uint32_t ks2,
                                           uint32_t B1, uint32_t B2, uint32_t B3,
                                           uint32_t B4, uint32_t B5,
                                           const uint32_t x1i[4], uint32_t o[4]) {
  uint32_t x0[4], x1[4];
#define RND(n)                                                      \
  _Pragma("unroll")                                                 \
  for (int m = 0; m < 4; ++m) {                                     \
    x0[m] += x1[m]; x1[m] = rotl32(x1[m], n) ^ x0[m];               \
  }
#define IRND(A, B, n)                                               \
  _Pragma("unroll")                                                 \
  for (int m = 0; m < 4; ++m) {                                     \
    uint32_t t = x1[m] + (B);                                       \
    x0[m] = add3s(x0[m], (A), t);                                   \
    x1[m] = rotl32(t, n) ^ x0[m];                                   \
  }
  // round 1 (x0 starts as k0; c0 == 0)
#pragma unroll
  for (int m = 0; m < 4; ++m) {
    x1[m] = x1i[m];
    x0[m] = k0 + x1[m];
    x1[m] = rotl32(x1[m], 13) ^ x0[m];
  }
  RND(15) RND(26) RND(6)
  IRND(k1, B1, 17) RND(29) RND(16) RND(24)
  IRND(ks2, B2, 13) RND(15) RND(26) RND(6)
  IRND(k0, B3, 17) RND(29) RND(16) RND(24)
  IRND(k1, B4, 13) RND(15) RND(26) RND(6)
#pragma unroll
  for (int m = 0; m < 4; ++m) o[m] = (x0[m] + ks2) ^ (x1[m] + B5);
#undef RND
#undef IRND
}

__device__ __forceinline__ float unit_from_bits(uint32_t bits) {
  return __uint_as_float((bits >> 9) | 0x3f800000u) - 1.0f;
}

__device__ __forceinline__ float raw_log2(float x) {
  float r;
  asm("v_log_f32 %0, %1" : "=v"(r) : "v"(x));
  return r;
}

__device__ __forceinline__ uint32_t min3_u32(uint32_t a, uint32_t b, uint32_t c) {
  uint32_t r;
  asm("v_min3_u32 %0, %1, %2, %3" : "=v"(r) : "v"(a), "v"(b), "v"(c));
  return r;
}

// ---------------------------------------------------------------------------
// Kernel A: per-face float4 (rP, 32*rP, rG, 32*rG), r = 1/(area+1e-12).
// Padded layout: NFP entries/batch; pad entries get +inf (packed key then
// lands >= 0x7F800000 and always loses the uint argmin; ties break to
// smaller j = real faces).
// ---------------------------------------------------------------------------
__global__ __launch_bounds__(256) void area_kernel(
    const float* __restrict__ pv, const int* __restrict__ pf,
    const float* __restrict__ gv, const int* __restrict__ gf,
    float4* __restrict__ FC) {
  int idx = blockIdx.x * 256 + threadIdx.x;
  if (idx >= NB * NFP) return;
  int b = idx / NFP;
  int f = idx - b * NFP;
  if (f >= NF) {
    float inf = __uint_as_float(0x7F800000u);
    FC[idx] = make_float4(inf, inf, inf, inf);
    return;
  }
  float r2[2];
#pragma unroll
  for (int half = 0; half < 2; ++half) {
    const float* verts = half == 0 ? pv + (size_t)b * NV * 3 : gv + (size_t)b * NV * 3;
    const int* faces   = half == 0 ? pf + (size_t)b * NF * 3 : gf + (size_t)b * NF * 3;
    int i0 = faces[3 * f + 0], i1 = faces[3 * f + 1], i2 = faces[3 * f + 2];
    float ax = verts[3 * i0], ay = verts[3 * i0 + 1], az = verts[3 * i0 + 2];
    float bx = verts[3 * i1], by = verts[3 * i1 + 1], bz = verts[3 * i1 + 2];
    float cx = verts[3 * i2], cy = verts[3 * i2 + 1], cz = verts[3 * i2 + 2];
    float e1x = bx - ax, e1y = by - ay, e1z = bz - az;
    float e2x = cx - ax, e2y = cy - ay, e2z = cz - az;
    float nx = e1y * e2z - e1z * e2y;
    float ny = e1z * e2x - e1x * e2z;
    float nz = e1x * e2y - e1y * e2x;
    float area = 0.5f * sqrtf(nx * nx + ny * ny + nz * nz);
    r2[half] = 1.0f / (area + 1e-12f);
  }
  FC[idx] = make_float4(r2[0], 32.0f * r2[0], r2[1], 32.0f * r2[1]);
}

// ---------------------------------------------------------------------------
// Kernel B: categorical sampling.  grid = rowgrp(64) x chunk(48).
// Block: 256 threads = 256 rows (one batch), one padded j-chunk of 288.
// Fused 4-way threefry; QL=72 compile-time quarter stride for ds offsets.
// ---------------------------------------------------------------------------
__global__ __launch_bounds__(256, 4) void cat_kernel(
    const float4* __restrict__ FC, unsigned int* __restrict__ mb, Keys K) {
  __shared__ float4 sFC[CHLP];
  int chunk = blockIdx.x % NCH;
  int rowgrp = blockIdx.x / NCH;        // [0, 64)
  int row = rowgrp * 256 + threadIdx.x; // [0, 16384)
  int b = rowgrp >> 4;                  // uniform per block
  int i = row & (NS - 1);
  int jstart = chunk * CHLP;
  uint32_t k0 = K.k1[2 * b], k1 = K.k1[2 * b + 1];
  uint32_t ks2 = k0 ^ k1 ^ 0x1BD11BDAu;
  uint32_t B1 = ks2 + 1u, B2 = k0 + 2u, B3 = k1 + 3u, B4 = ks2 + 4u, B5 = k0 + 5u;

  const float4* __restrict__ fcg = FC + (size_t)b * NFP + jstart;
  for (int t = threadIdx.x; t < CHLP; t += 256) sFC[t] = fcg[t];
  __syncthreads();

  uint32_t cbase = (uint32_t)i * (uint32_t)NF + (uint32_t)jstart;
  uint32_t bestP = 0xFFFFFFFFu, bestG = 0xFFFFFFFFu;

  // incrementing per-chain counter registers: x1i[m] = c1(m) + k1
  uint32_t x1i[4];
  x1i[0] = cbase + k1;
  x1i[1] = x1i[0] + (uint32_t)QL;
  x1i[2] = x1i[0] + (uint32_t)(2 * QL);
  x1i[3] = x1i[0] + (uint32_t)(3 * QL);
  uint32_t jj0 = (uint32_t)jstart;

  for (int k = 0; k < QL; ++k) {
    uint32_t o[4];
    tf2x32_x4f(k0, k1, ks2, B1, B2, B3, B4, B5, x1i, o);
    uint32_t kp[4], kg[4];
#pragma unroll
    for (int m = 0; m < 4; ++m) {
      float f1 = (float)o[m];              // v_cvt_f32_u32
      float l1 = raw_log2(f1);             // bits=0 -> -inf -> +inf key, loses
      float4 r1 = sFC[k + m * QL];         // wave-uniform ds_read_b128, imm offs
      uint32_t jm = jj0 + (uint32_t)(m * QL);
      // score = 32*r - log2(bits)*r  (>= 0), single v_fma with -src modifier,
      // then (score & ~IDXMASK) | j in one v_and_or_b32.
      kp[m] = and_or_s(__float_as_uint(fmaf(-l1, r1.x, r1.y)), ~IDXMASK, jm);
      kg[m] = and_or_s(__float_as_uint(fmaf(-l1, r1.z, r1.w)), ~IDXMASK, jm);
    }
    bestP = min3_u32(min3_u32(bestP, kp[0], kp[1]), kp[2], kp[3]);
    bestG = min3_u32(min3_u32(bestG, kg[0], kg[1]), kg[2], kg[3]);
#pragma unroll
    for (int m = 0; m < 4; ++m) x1i[m] += 1u;
    jj0 += 1u;
  }
  atomicMin(&mb[row], bestP);
  atomicMin(&mb[NB * NS + row], bestG);
}

// ---------------------------------------------------------------------------
// Kernel C: build sampled points for all 8 meshes. u,w shared pred/gt.
// ---------------------------------------------------------------------------
__global__ __launch_bounds__(256) void pts_kernel(
    const float* __restrict__ pv, const int* __restrict__ pf,
    const float* __restrict__ gv, const int* __restrict__ gf,
    const unsigned int* __restrict__ mb, float* __restrict__ pts, Keys K) {
  int idx = blockIdx.x * 256 + threadIdx.x;
  if (idx >= NB * NS) return;
  int b = idx >> 12;
  int i = idx & (NS - 1);

  uint32_t a0, a1, ub, wb;
  tf2x32(K.k2[2 * b], K.k2[2 * b + 1], 0u, (uint32_t)i, a0, a1); ub = a0 ^ a1;
  tf2x32(K.k3[2 * b], K.k3[2 * b + 1], 0u, (uint32_t)i, a0, a1); wb = a0 ^ a1;

  float u = unit_from_bits(ub);
  float w = unit_from_bits(wb);
  float r = sqrtf(u);
  float c0 = 1.0f - r;
  float c1 = r * (1.0f - w);
  float c2 = r * w;

#pragma unroll
  for (int half = 0; half < 2; ++half) {
    const float* verts = half == 0 ? pv + (size_t)b * NV * 3 : gv + (size_t)b * NV * 3;
    const int* faces   = half == 0 ? pf + (size_t)b * NF * 3 : gf + (size_t)b * NF * 3;
    int mesh = half == 0 ? b : NB + b;
    int f = (int)(mb[(size_t)mesh * NS + i] & IDXMASK);
    int i0 = faces[3 * f + 0], i1 = faces[3 * f + 1], i2 = faces[3 * f + 2];
    float* dst = pts + ((size_t)mesh * NS + i) * 3;
#pragma unroll
    for (int c = 0; c < 3; ++c) {
      float v0 = verts[3 * i0 + c];
      float v1 = verts[3 * i1 + c];
      float v2 = verts[3 * i2 + c];
      dst[c] = c0 * v0 + c1 * v1 + c2 * v2;
    }
  }
}

// ---------------------------------------------------------------------------
// Kernel D: two-way chamfer partial-min. 1024 blocks; 512-pt LDS DB tile.
// ---------------------------------------------------------------------------
#define DBC 8
#define DBL (NS / DBC)   // 512
__global__ __launch_bounds__(256) void chamfer_min_kernel(
    const float* __restrict__ pts, unsigned int* __restrict__ cmin) {
  int blk = blockIdx.x;
  int dchunk = blk & (DBC - 1);
  int rest = blk >> 3;
  int chunk = rest & 15;
  int mb_ = rest >> 4;
  int dir = mb_ >> 2, b = mb_ & 3;
  int qm = (dir == 0) ? b : NB + b;
  int dm = (dir == 0) ? NB + b : b;

  __shared__ float4 db[DBL];
  const float* dbp = pts + ((size_t)dm * NS + dchunk * DBL) * 3;
  for (int j = threadIdx.x; j < DBL; j += 256) {
    float x = dbp[3 * j], y = dbp[3 * j + 1], z = dbp[3 * j + 2];
    db[j] = make_float4(x, y, z, x * x + y * y + z * z);
  }
  __syncthreads();

  int q = chunk * 256 + threadIdx.x;
  const float* qp = pts + ((size_t)qm * NS + q) * 3;
  float px = qp[0], py = qp[1], pz = qp[2];
  float pp = px * px + py * py + pz * pz;
  float m = INFINITY;
  for (int j = 0; j < DBL; ++j) {
    float4 t = db[j];
    float d = (pp + t.w) - 2.0f * (px * t.x + py * t.y + pz * t.z);
    m = fminf(m, d);
  }
  m = fmaxf(m, 0.0f);
  atomicMin(&cmin[(size_t)(dir * NB + b) * NS + q], __float_as_uint(m));
}

// ---------------------------------------------------------------------------
// Kernel E: sum 2*NB*NS mins -> loss.  64 blocks, wave-reduce + atomicAdd.
// ---------------------------------------------------------------------------
__global__ __launch_bounds__(256) void chamfer_sum_kernel(
    const unsigned int* __restrict__ cmin, float* __restrict__ out) {
  int idx = blockIdx.x * 256 + threadIdx.x;
  float s = __uint_as_float(cmin[idx]) + __uint_as_float(cmin[idx + 16384]);
  for (int off = 32; off > 0; off >>= 1) s += __shfl_down(s, off);
  if ((threadIdx.x & 63) == 0) atomicAdd(out, s * (1.0f / 16384.0f));
}

// ---------------------------------------------------------------------------
extern "C" void kernel_launch(void* const* d_in, const int* in_sizes, int n_in,
                              void* d_out, int out_size, void* d_ws, size_t ws_size,
                              hipStream_t stream) {
  const float* pv = (const float*)d_in[0];
  const int* pf = (const int*)d_in[1];
  const float* gv = (const float*)d_in[2];
  const int* gf = (const int*)d_in[3];
  float* out = (float*)d_out;

  float4* FC = (float4*)d_ws;                                      // 884,736 B
  unsigned int* mb = (unsigned int*)((char*)d_ws + 896 * 1024);    // 131,072 B
  unsigned int* cmin = (unsigned int*)((char*)d_ws + 1024 * 1024); // 131,072 B
  float* pts = (float*)((char*)d_ws + 1152 * 1024);                // 393,216 B

  Keys K;
  for (int b = 0; b < NB; ++b) {
    uint32_t kb0, kb1;
    tf2x32(0u, 42u, 0u, (uint32_t)b, kb0, kb1);
    tf2x32(kb0, kb1, 0u, 0u, K.k1[2 * b], K.k1[2 * b + 1]);
    tf2x32(kb0, kb1, 0u, 1u, K.k2[2 * b], K.k2[2 * b + 1]);
    tf2x32(kb0, kb1, 0u, 2u, K.k3[2 * b], K.k3[2 * b + 1]);
  }

  hipMemsetAsync(mb, 0xFF, 256 * 1024, stream);   // both min buffers
  hipMemsetAsync(out, 0, sizeof(float), stream);

  area_kernel<<<(NB * NFP) / 256, 256, 0, stream>>>(pv, pf, gv, gf, FC);
  cat_kernel<<<64 * NCH, 256, 0, stream>>>(FC, mb, K);   // 3072 blocks
  pts_kernel<<<(NB * NS + 255) / 256, 256, 0, stream>>>(pv, pf, gv, gf, mb, pts, K);
  chamfer_min_kernel<<<2 * NB * 16 * DBC, 256, 0, stream>>>(pts, cmin);
  chamfer_sum_kernel<<<64, 256, 0, stream>>>(cmin, out);
}